// Round 1
// baseline (93.025 us; speedup 1.0000x reference)
//
#include <hip/hip_runtime.h>
#include <cstdint>

typedef unsigned int u32;
typedef unsigned short u16;
typedef unsigned long long u64;
typedef __attribute__((ext_vector_type(4))) float f32x4;
typedef __attribute__((ext_vector_type(8))) short s16x8;

#define B_SZ   512
#define D_IN   784
#define D_H    2048
#define D_O    10
#define T_STEPS 100

static __device__ __forceinline__ u16 f2bf_rn(float f) {
  u32 u = __float_as_uint(f);
  u32 r = u + 0x7FFFu + ((u >> 16) & 1u);   // round-to-nearest-even on magnitude
  return (u16)(r >> 16);
}
static __device__ __forceinline__ float bf2f(u16 h) {
  return __uint_as_float(((u32)h) << 16);
}

// ---------------------------------------------------------------------------
// K0: split W2 (f32) into bf16 hi/lo pair, pre-laid-out as MFMA B-fragments.
// For 16x16x32 bf16 MFMA, lane l needs B[k = kb*32 + (l>>4)*8 + i][col = l&15],
// with B[k][o] = W2[o][k]. We store P[(kb*64 + l)*4 + p] packing elems 2p,2p+1.
// Cols o >= 10 are zero (padding).
// ---------------------------------------------------------------------------
__global__ __launch_bounds__(256) void k_prep(const float* __restrict__ W2,
                                              u32* __restrict__ Phi,
                                              u32* __restrict__ Plo) {
  int t = blockIdx.x * 256 + threadIdx.x;
  if (t >= 64 * 64) return;
  int kb = t >> 6, l = t & 63;
  int o = l & 15;
  int kbase = kb * 32 + ((l >> 4) << 3);
  u32 hw[4], lw[4];
#pragma unroll
  for (int p = 0; p < 4; ++p) {
    u32 hp = 0, lp = 0;
#pragma unroll
    for (int q = 0; q < 2; ++q) {
      float f = (o < D_O) ? W2[o * D_H + kbase + 2 * p + q] : 0.0f;
      u16 h = f2bf_rn(f);
      float rres = __fsub_rn(f, bf2f(h));
      u16 lo = f2bf_rn(rres);
      hp |= ((u32)h) << (16 * q);
      lp |= ((u32)lo) << (16 * q);
    }
    hw[p] = hp; lw[p] = lp;
  }
  int base = (kb * 64 + l) * 4;
#pragma unroll
  for (int p = 0; p < 4; ++p) { Phi[base + p] = hw[p]; Plo[base + p] = lw[p]; }
}

// ---------------------------------------------------------------------------
// K1: cur1 = x @ W1^T + b1   (f32, 512x2048, K=784).  64x64 tile per WG,
// 256 threads, 4x4 outputs/thread, BK=16 staged in LDS (both operands are
// K-innermost so we transpose on the LDS store).
// ---------------------------------------------------------------------------
__global__ __launch_bounds__(256) void k_cur1(const float* __restrict__ x,
                                              const float* __restrict__ W1,
                                              const float* __restrict__ b1,
                                              float* __restrict__ cur1) {
  __shared__ float sa[16][68];
  __shared__ float sb[16][68];
  const int t = threadIdx.x;
  const int m0 = blockIdx.y * 64, n0 = blockIdx.x * 64;
  const int lr = t >> 2;            // 0..63 row of tile being staged
  const int lk = (t & 3) * 4;       // 0,4,8,12  k-offset staged
  const int tm = (t & 15) * 4;      // m-offset computed
  const int tn = (t >> 4) * 4;      // n-offset computed
  float acc[4][4] = {};
  for (int k0 = 0; k0 < D_IN; k0 += 16) {
    float4 av = *(const float4*)(x  + (size_t)(m0 + lr) * D_IN + k0 + lk);
    float4 bv = *(const float4*)(W1 + (size_t)(n0 + lr) * D_IN + k0 + lk);
    __syncthreads();
    sa[lk + 0][lr] = av.x; sa[lk + 1][lr] = av.y; sa[lk + 2][lr] = av.z; sa[lk + 3][lr] = av.w;
    sb[lk + 0][lr] = bv.x; sb[lk + 1][lr] = bv.y; sb[lk + 2][lr] = bv.z; sb[lk + 3][lr] = bv.w;
    __syncthreads();
#pragma unroll
    for (int kk = 0; kk < 16; ++kk) {
      float4 a = *(const float4*)&sa[kk][tm];
      float4 b = *(const float4*)&sb[kk][tn];
#pragma unroll
      for (int i = 0; i < 4; ++i) {
        float ai = (i == 0) ? a.x : (i == 1) ? a.y : (i == 2) ? a.z : a.w;
        acc[i][0] += ai * b.x; acc[i][1] += ai * b.y;
        acc[i][2] += ai * b.z; acc[i][3] += ai * b.w;
      }
    }
  }
  float4 b1v = *(const float4*)(b1 + n0 + tn);
#pragma unroll
  for (int i = 0; i < 4; ++i) {
    float4 v;
    v.x = acc[i][0] + b1v.x; v.y = acc[i][1] + b1v.y;
    v.z = acc[i][2] + b1v.z; v.w = acc[i][3] + b1v.w;
    *(float4*)(cur1 + (size_t)(m0 + tm + i) * D_H + n0 + tn) = v;
  }
}

// ---------------------------------------------------------------------------
// K2: fused temporal kernel. One WG (256 thr) per batch row.
//  B: per-neuron 100-step leaky recurrence -> spike bit-matrix bits[t][h/32]
//  C: cur2[t][o] = sum_h spk1[t][h] * W2[o][h]  via bf16 hi/lo MFMA pairs
//  D: layer-2 recurrence + spike-mean + softmax
// ---------------------------------------------------------------------------
__global__ __launch_bounds__(256) void k_snn(const float* __restrict__ cur1,
                                             const u32* __restrict__ Phi,
                                             const u32* __restrict__ Plo,
                                             const float* __restrict__ b2,
                                             const float* __restrict__ beta1p,
                                             const float* __restrict__ beta2p,
                                             float* __restrict__ out) {
  __shared__ u32  bits[112][65];   // [t][h/32], rows 100..111 zero (A-pad)
  __shared__ float c2[112][17];    // cur2[t][o] (cols 10..15 = 0)
  const int b = blockIdx.x;
  const int tid = threadIdx.x;
  const int wave = tid >> 6, lane = tid & 63;
  const float b1c = fminf(fmaxf(beta1p[0], 0.0f), 1.0f);
  const float b2c = fminf(fmaxf(beta2p[0], 0.0f), 1.0f);

  // zero the A-padding rows (t = 100..111)
  for (int idx = tid; idx < 12 * 65; idx += 256) bits[100 + idx / 65][idx % 65] = 0;

  // ---- phase B: layer-1 recurrence, exact numpy op order ----
  float cv[8], memv[8];
  bool sp[8];
#pragma unroll
  for (int j = 0; j < 8; ++j) {
    cv[j] = cur1[(size_t)b * D_H + j * 256 + tid];
    memv[j] = 0.0f; sp[j] = false;
  }
  for (int t = 0; t < T_STEPS; ++t) {
#pragma unroll
    for (int j = 0; j < 8; ++j) {
      float m = __fmul_rn(b1c, memv[j]);
      m = __fadd_rn(m, cv[j]);
      if (sp[j]) m = __fsub_rn(m, 1.0f);   // reset (subtract), exact since THR=1
      sp[j] = (m > 1.0f);
      memv[j] = m;
      u64 msk = __ballot(sp[j]);
      if ((lane & 31) == 0)
        bits[t][j * 8 + wave * 2 + (lane >> 5)] = (u32)(msk >> (lane & 32));
    }
  }
  __syncthreads();

  // ---- phase C: cur2 via MFMA, K = 2048 (64 steps of 32) ----
  f32x4 acc0 = {0.f, 0.f, 0.f, 0.f}, acc1 = {0.f, 0.f, 0.f, 0.f};
  const int row0 = wave * 16 + (lane & 15);        // A-row (=t) for tile `wave`
  const int row1 = (wave + 4) * 16 + (lane & 15);  // tile wave+4 (if exists)
  const int shift = (lane >> 4) * 8;               // k-offset within 32-bit word
  const bool two = (wave < 3);                     // 7 tiles total (t up to 111)
  for (int kb = 0; kb < 64; ++kb) {
    const uint4 bh = *(const uint4*)(Phi + (size_t)(kb * 64 + lane) * 4);
    const uint4 bl = *(const uint4*)(Plo + (size_t)(kb * 64 + lane) * 4);
    u32 w0 = bits[row0][kb] >> shift;
    u32 w1 = two ? (bits[row1][kb] >> shift) : 0u;
    uint4 a0u, a1u;
#pragma unroll
    for (int p = 0; p < 4; ++p) {
      u32 v0 = ((w0 >> (2 * p)) & 1u) * 0x3F80u | ((w0 >> (2 * p + 1)) & 1u) * 0x3F800000u;
      u32 v1 = ((w1 >> (2 * p)) & 1u) * 0x3F80u | ((w1 >> (2 * p + 1)) & 1u) * 0x3F800000u;
      ((u32*)&a0u)[p] = v0; ((u32*)&a1u)[p] = v1;
    }
    s16x8 a0  = __builtin_bit_cast(s16x8, a0u);
    s16x8 a1  = __builtin_bit_cast(s16x8, a1u);
    s16x8 bhi = __builtin_bit_cast(s16x8, bh);
    s16x8 blo = __builtin_bit_cast(s16x8, bl);
    acc0 = __builtin_amdgcn_mfma_f32_16x16x32_bf16(a0, bhi, acc0, 0, 0, 0);
    acc0 = __builtin_amdgcn_mfma_f32_16x16x32_bf16(a0, blo, acc0, 0, 0, 0);
    if (two) {
      acc1 = __builtin_amdgcn_mfma_f32_16x16x32_bf16(a1, bhi, acc1, 0, 0, 0);
      acc1 = __builtin_amdgcn_mfma_f32_16x16x32_bf16(a1, blo, acc1, 0, 0, 0);
    }
  }
  {
    // C/D layout: col = lane&15, row = (lane>>4)*4 + reg   [m89-verified]
    const int colw = lane & 15, rbase = (lane >> 4) * 4;
#pragma unroll
    for (int r = 0; r < 4; ++r) c2[wave * 16 + rbase + r][colw] = acc0[r];
    if (two) {
#pragma unroll
      for (int r = 0; r < 4; ++r) c2[(wave + 4) * 16 + rbase + r][colw] = acc1[r];
    }
  }
  __syncthreads();

  // ---- phase D: layer-2 recurrence + mean + softmax (lanes 0..15 of wave 0)
  if (tid < 16) {
    const int o = tid;
    const bool valid = (o < D_O);
    const float bb = valid ? b2[o] : 0.0f;
    float m2 = 0.0f; bool s2 = false; int cnt = 0;
    for (int t = 0; t < T_STEPS; ++t) {
      float cc = __fadd_rn(c2[t][o], bb);
      float m = __fadd_rn(__fmul_rn(b2c, m2), cc);
      if (s2) m = __fsub_rn(m, 1.0f);
      s2 = (m > 1.0f);
      m2 = m;
      cnt += s2 ? 1 : 0;
    }
    float mean = valid ? ((float)cnt / 100.0f) : -1e30f;
    float mx = mean;
#pragma unroll
    for (int i = 8; i >= 1; i >>= 1) mx = fmaxf(mx, __shfl_xor(mx, i, 16));
    float e = valid ? expf(mean - mx) : 0.0f;
    float s = e;
#pragma unroll
    for (int i = 8; i >= 1; i >>= 1) s = __fadd_rn(s, __shfl_xor(s, i, 16));
    if (valid) out[(size_t)b * D_O + o] = e / s;
  }
}

// ---------------------------------------------------------------------------
extern "C" void kernel_launch(void* const* d_in, const int* in_sizes, int n_in,
                              void* d_out, int out_size, void* d_ws, size_t ws_size,
                              hipStream_t stream) {
  const float* x     = (const float*)d_in[0];
  const float* W1    = (const float*)d_in[1];
  const float* b1    = (const float*)d_in[2];
  const float* W2    = (const float*)d_in[3];
  const float* b2    = (const float*)d_in[4];
  const float* beta1 = (const float*)d_in[5];
  const float* beta2 = (const float*)d_in[6];
  float* out = (float*)d_out;

  char* ws = (char*)d_ws;
  float* cur1 = (float*)ws;                              // 512*2048*4 = 4 MiB
  u32*   Phi  = (u32*)(ws + 4194304);                    // 64 KiB
  u32*   Plo  = (u32*)(ws + 4194304 + 65536);            // 64 KiB

  hipLaunchKernelGGL(k_prep, dim3(16), dim3(256), 0, stream, W2, Phi, Plo);
  hipLaunchKernelGGL(k_cur1, dim3(32, 8), dim3(256), 0, stream, x, W1, b1, cur1);
  hipLaunchKernelGGL(k_snn, dim3(512), dim3(256), 0, stream,
                     cur1, Phi, Plo, b2, beta1, beta2, out);
}

// Round 3
// 89.272 us; speedup vs baseline: 1.0420x; 1.0420x over previous
//
#include <hip/hip_runtime.h>
#include <cstdint>

typedef unsigned int u32;
typedef unsigned short u16;
typedef unsigned long long u64;
typedef __attribute__((ext_vector_type(4))) float f32x4;
typedef __attribute__((ext_vector_type(8))) short s16x8;

#define D_IN   784
#define D_H    2048
#define D_O    10
#define T_STEPS 100
#define KB1    25          // ceil(784/32) k-blocks for layer-1 GEMM

static __device__ __forceinline__ u16 f2bf_rn(float f) {
  u32 u = __float_as_uint(f);
  u32 r = u + 0x7FFFu + ((u >> 16) & 1u);
  return (u16)(r >> 16);
}
static __device__ __forceinline__ float bf2f(u16 h) {
  return __uint_as_float(((u32)h) << 16);
}

// ---------------------------------------------------------------------------
// K0a: W2 (f32) -> bf16 hi/lo MFMA B-fragments (round-1 verified).
// ---------------------------------------------------------------------------
__global__ __launch_bounds__(256) void k_prep_w2(const float* __restrict__ W2,
                                                 u32* __restrict__ Phi,
                                                 u32* __restrict__ Plo) {
  int t = blockIdx.x * 256 + threadIdx.x;
  if (t >= 64 * 64) return;
  int kb = t >> 6, l = t & 63;
  int o = l & 15;
  int kbase = kb * 32 + ((l >> 4) << 3);
  u32 hw[4], lw[4];
#pragma unroll
  for (int p = 0; p < 4; ++p) {
    u32 hp = 0, lp = 0;
#pragma unroll
    for (int q = 0; q < 2; ++q) {
      float f = (o < D_O) ? W2[o * D_H + kbase + 2 * p + q] : 0.0f;
      u16 h = f2bf_rn(f);
      float rr = __fsub_rn(f, bf2f(h));
      u16 lo = f2bf_rn(rr);
      hp |= ((u32)h) << (16 * q);
      lp |= ((u32)lo) << (16 * q);
    }
    hw[p] = hp; lw[p] = lp;
  }
  int base = (kb * 64 + l) * 4;
#pragma unroll
  for (int p = 0; p < 4; ++p) { Phi[base + p] = hw[p]; Plo[base + p] = lw[p]; }
}

// ---------------------------------------------------------------------------
// K0b: triple-split x and W1 into bf16 MFMA fragments (A-frags for x, B-frags
// for W1), K padded 784->800. Element (frag, lane l): row = frag*16 + (l&15),
// k = kb*32 + (l>>4)*8 + e, e=0..7 packed as bf16 pairs into uint4.
// ---------------------------------------------------------------------------
__global__ __launch_bounds__(256) void k_split(const float* __restrict__ x,
                                               const float* __restrict__ W1,
                                               uint4* __restrict__ Xs,
                                               uint4* __restrict__ Ws) {
  int t = blockIdx.x * 256 + threadIdx.x;
  const int XT = KB1 * 32 * 64;     // 51200
  const int WT = KB1 * 128 * 64;    // 204800
  if (t >= XT + WT) return;
  const float* base; uint4* dst; int kb, l, frag, nfr;
  if (t < XT) {
    l = t & 63; int f = t >> 6; frag = f & 31; kb = f >> 5;
    base = x; dst = Xs; nfr = 32;
  } else {
    int t2 = t - XT;
    l = t2 & 63; int f = t2 >> 6; frag = f & 127; kb = f >> 7;
    base = W1; dst = Ws; nfr = 128;
  }
  int row = frag * 16 + (l & 15);
  int ks = kb * 32 + ((l >> 4) << 3);
  const float* rp = base + (size_t)row * D_IN;
  float e[8];
#pragma unroll
  for (int q = 0; q < 8; ++q) e[q] = (ks + q < D_IN) ? rp[ks + q] : 0.0f;
  u32 w0[4], w1[4], w2[4];
#pragma unroll
  for (int p = 0; p < 4; ++p) {
    u32 a0 = 0, a1 = 0, a2 = 0;
#pragma unroll
    for (int q = 0; q < 2; ++q) {
      float v = e[2 * p + q];
      u16 s0 = f2bf_rn(v); float r1 = __fsub_rn(v, bf2f(s0));
      u16 s1 = f2bf_rn(r1); float r2 = __fsub_rn(r1, bf2f(s1));
      u16 s2 = f2bf_rn(r2);
      a0 |= ((u32)s0) << (16 * q);
      a1 |= ((u32)s1) << (16 * q);
      a2 |= ((u32)s2) << (16 * q);
    }
    w0[p] = a0; w1[p] = a1; w2[p] = a2;
  }
  size_t bi = ((size_t)kb * nfr + frag) * 64 + l;
  size_t ss = (size_t)KB1 * nfr * 64;
  dst[0 * ss + bi] = make_uint4(w0[0], w0[1], w0[2], w0[3]);
  dst[1 * ss + bi] = make_uint4(w1[0], w1[1], w1[2], w1[3]);
  dst[2 * ss + bi] = make_uint4(w2[0], w2[1], w2[2], w2[3]);
}

// ---------------------------------------------------------------------------
// K1: cur1 = x @ W1^T + b1 via 6-product bf16-triple MFMA.
// WG = 512 thr (8 waves), tile 64m x 64n. Waves 0-3: even kb, n-frag w;
// waves 4-7: odd kb, n-frag w-4. Combine halves through LDS at the end.
// ---------------------------------------------------------------------------
__global__ __launch_bounds__(512) void k_gemm1(const uint4* __restrict__ Xs,
                                               const uint4* __restrict__ Ws,
                                               const float* __restrict__ b1,
                                               float* __restrict__ cur1) {
  __shared__ float4 comb[16][64];   // 16 KB
  const int tid = threadIdx.x, wave = tid >> 6, lane = tid & 63;
  const int mb = blockIdx.y, nb = blockIdx.x;
  const int wn = wave & 3;
  const int nfrag = nb * 4 + wn;
  const size_t ssx = (size_t)KB1 * 32 * 64;
  const size_t ssw = (size_t)KB1 * 128 * 64;
  f32x4 acc[4] = {{0.f,0.f,0.f,0.f},{0.f,0.f,0.f,0.f},{0.f,0.f,0.f,0.f},{0.f,0.f,0.f,0.f}};
  for (int kb = (wave >> 2); kb < KB1; kb += 2) {
    const size_t bb = (size_t)kb * 8192 + (size_t)nfrag * 64 + lane;
    uint4 b0u = Ws[0 * ssw + bb];
    uint4 b1u = Ws[1 * ssw + bb];
    uint4 b2u = Ws[2 * ssw + bb];
    s16x8 B0 = __builtin_bit_cast(s16x8, b0u);
    s16x8 B1 = __builtin_bit_cast(s16x8, b1u);
    s16x8 B2 = __builtin_bit_cast(s16x8, b2u);
#pragma unroll
    for (int fm = 0; fm < 4; ++fm) {
      const size_t ab = (size_t)kb * 2048 + (size_t)(mb * 4 + fm) * 64 + lane;
      uint4 a0u = Xs[0 * ssx + ab];
      uint4 a1u = Xs[1 * ssx + ab];
      uint4 a2u = Xs[2 * ssx + ab];
      s16x8 A0 = __builtin_bit_cast(s16x8, a0u);
      s16x8 A1 = __builtin_bit_cast(s16x8, a1u);
      s16x8 A2 = __builtin_bit_cast(s16x8, a2u);
      acc[fm] = __builtin_amdgcn_mfma_f32_16x16x32_bf16(A0, B0, acc[fm], 0, 0, 0);
      acc[fm] = __builtin_amdgcn_mfma_f32_16x16x32_bf16(A0, B1, acc[fm], 0, 0, 0);
      acc[fm] = __builtin_amdgcn_mfma_f32_16x16x32_bf16(A1, B0, acc[fm], 0, 0, 0);
      acc[fm] = __builtin_amdgcn_mfma_f32_16x16x32_bf16(A1, B1, acc[fm], 0, 0, 0);
      acc[fm] = __builtin_amdgcn_mfma_f32_16x16x32_bf16(A0, B2, acc[fm], 0, 0, 0);
      acc[fm] = __builtin_amdgcn_mfma_f32_16x16x32_bf16(A2, B0, acc[fm], 0, 0, 0);
    }
  }
  if (wave >= 4) {
#pragma unroll
    for (int fm = 0; fm < 4; ++fm) {
      comb[wn * 4 + fm][lane] = make_float4(acc[fm][0], acc[fm][1], acc[fm][2], acc[fm][3]);
    }
  }
  __syncthreads();
  if (wave < 4) {
    const float bv = b1[nfrag * 16 + (lane & 15)];
    const int rbase = (lane >> 4) * 4, col = lane & 15;
#pragma unroll
    for (int fm = 0; fm < 4; ++fm) {
      float4 o = comb[wn * 4 + fm][lane];
      float v[4] = {acc[fm][0] + o.x, acc[fm][1] + o.y, acc[fm][2] + o.z, acc[fm][3] + o.w};
#pragma unroll
      for (int r = 0; r < 4; ++r) {
        int m = mb * 64 + fm * 16 + rbase + r;
        cur1[(size_t)m * D_H + nfrag * 16 + col] = v[r] + bv;
      }
    }
  }
}

// ---------------------------------------------------------------------------
// K2: fused temporal kernel, 512 thr/block, one block per batch row.
// ---------------------------------------------------------------------------
__global__ __launch_bounds__(512) void k_snn(const float* __restrict__ cur1,
                                             const u32* __restrict__ Phi,
                                             const u32* __restrict__ Plo,
                                             const float* __restrict__ b2,
                                             const float* __restrict__ beta1p,
                                             const float* __restrict__ beta2p,
                                             float* __restrict__ out) {
  __shared__ __align__(16) u32 bits[112][66];   // [t][h/32], stride 66 (b64-aligned, bank-spread)
  __shared__ float c2[112][18];
  const int b = blockIdx.x;
  const int tid = threadIdx.x;
  const int wave = tid >> 6, lane = tid & 63;
  const float b1c = fminf(fmaxf(beta1p[0], 0.0f), 1.0f);
  const float b2c = fminf(fmaxf(beta2p[0], 0.0f), 1.0f);

  for (int idx = tid; idx < 12 * 66; idx += 512) bits[100 + idx / 66][idx % 66] = 0;

  // ---- phase B: layer-1 recurrence (4 neurons/thread), exact numpy op order
  float cv[4], memv[4];
  bool sp[4];
#pragma unroll
  for (int j = 0; j < 4; ++j) {
    cv[j] = cur1[(size_t)b * D_H + j * 512 + tid];
    memv[j] = 0.0f; sp[j] = false;
  }
  for (int t = 0; t < T_STEPS; ++t) {
    u64 msk[4];
#pragma unroll
    for (int j = 0; j < 4; ++j) {
      float m = __fmul_rn(b1c, memv[j]);
      m = __fadd_rn(m, cv[j]);
      if (sp[j]) m = __fsub_rn(m, 1.0f);
      sp[j] = (m > 1.0f);
      memv[j] = m;
      msk[j] = __ballot(sp[j]);
    }
    if (lane == 0) {
      u64* rowp = (u64*)&bits[t][0];
      rowp[0 * 8 + wave] = msk[0];
      rowp[1 * 8 + wave] = msk[1];
      rowp[2 * 8 + wave] = msk[2];
      rowp[3 * 8 + wave] = msk[3];
    }
  }
  __syncthreads();

  // ---- phase C: cur2 via MFMA (waves 0..6, one 16-row tile each)
  if (wave < 7) {
    f32x4 acc = {0.f, 0.f, 0.f, 0.f};
    const int row0 = wave * 16 + (lane & 15);
    const int shift = (lane >> 4) * 8;
    for (int kb = 0; kb < 64; ++kb) {
      const uint4 bh = *(const uint4*)(Phi + (size_t)(kb * 64 + lane) * 4);
      const uint4 bl = *(const uint4*)(Plo + (size_t)(kb * 64 + lane) * 4);
      u32 w0 = bits[row0][kb] >> shift;
      uint4 a0u;
#pragma unroll
      for (int p = 0; p < 4; ++p) {
        u32 v0 = ((w0 >> (2 * p)) & 1u) * 0x3F80u | ((w0 >> (2 * p + 1)) & 1u) * 0x3F800000u;
        ((u32*)&a0u)[p] = v0;
      }
      s16x8 a0  = __builtin_bit_cast(s16x8, a0u);
      s16x8 bhi = __builtin_bit_cast(s16x8, bh);
      s16x8 blo = __builtin_bit_cast(s16x8, bl);
      acc = __builtin_amdgcn_mfma_f32_16x16x32_bf16(a0, bhi, acc, 0, 0, 0);
      acc = __builtin_amdgcn_mfma_f32_16x16x32_bf16(a0, blo, acc, 0, 0, 0);
    }
    const int colw = lane & 15, rbase = (lane >> 4) * 4;
#pragma unroll
    for (int r = 0; r < 4; ++r) c2[wave * 16 + rbase + r][colw] = acc[r];
  }
  __syncthreads();

  // ---- phase D: layer-2 recurrence + mean + softmax (batched c2 reads)
  if (tid < 16) {
    const int o = tid;
    const bool valid = (o < D_O);
    const float bb = valid ? b2[o] : 0.0f;
    float m2 = 0.0f; bool s2 = false; int cnt = 0;
    for (int t0 = 0; t0 < T_STEPS; t0 += 10) {
      float cc[10];
#pragma unroll
      for (int i = 0; i < 10; ++i) cc[i] = c2[t0 + i][o];
#pragma unroll
      for (int i = 0; i < 10; ++i) {
        float c = __fadd_rn(cc[i], bb);
        float m = __fadd_rn(__fmul_rn(b2c, m2), c);
        if (s2) m = __fsub_rn(m, 1.0f);
        s2 = (m > 1.0f);
        m2 = m;
        cnt += s2 ? 1 : 0;
      }
    }
    float mean = valid ? ((float)cnt / 100.0f) : -1e30f;
    float mx = mean;
#pragma unroll
    for (int i = 8; i >= 1; i >>= 1) mx = fmaxf(mx, __shfl_xor(mx, i, 16));
    float e = valid ? expf(mean - mx) : 0.0f;
    float s = e;
#pragma unroll
    for (int i = 8; i >= 1; i >>= 1) s = __fadd_rn(s, __shfl_xor(s, i, 16));
    if (valid) out[(size_t)b * D_O + o] = e / s;
  }
}

// ---------------------------------------------------------------------------
extern "C" void kernel_launch(void* const* d_in, const int* in_sizes, int n_in,
                              void* d_out, int out_size, void* d_ws, size_t ws_size,
                              hipStream_t stream) {
  const float* x     = (const float*)d_in[0];
  const float* W1    = (const float*)d_in[1];
  const float* b1    = (const float*)d_in[2];
  const float* W2    = (const float*)d_in[3];
  const float* b2    = (const float*)d_in[4];
  const float* beta1 = (const float*)d_in[5];
  const float* beta2 = (const float*)d_in[6];
  float* out = (float*)d_out;

  char* ws = (char*)d_ws;
  float* cur1 = (float*)ws;                           // 4,194,304 B
  u32*   Phi  = (u32*)(ws + 4194304);                 // 65,536 B
  u32*   Plo  = (u32*)(ws + 4194304 + 65536);         // 65,536 B
  uint4* Xs   = (uint4*)(ws + 4325376);               // 2,457,600 B
  uint4* Ws_  = (uint4*)(ws + 6782976);               // 9,830,400 B (ends ~15.9 MiB)

  hipLaunchKernelGGL(k_prep_w2, dim3(16), dim3(256), 0, stream, W2, Phi, Plo);
  hipLaunchKernelGGL(k_split, dim3(1000), dim3(256), 0, stream, x, W1, Xs, Ws_);
  hipLaunchKernelGGL(k_gemm1, dim3(32, 8), dim3(512), 0, stream, Xs, Ws_, b1, cur1);
  hipLaunchKernelGGL(k_snn, dim3(512), dim3(512), 0, stream,
                     cur1, Phi, Plo, b2, beta1, beta2, out);
}